// Round 5
// baseline (291.859 us; speedup 1.0000x reference)
//
#include <hip/hip_runtime.h>
#include <math.h>

// BoundaryFocalLoss: B=128, T=200000, f32 inputs, i32 targets, f32 mask -> scalar f32.
// ~307 MB mandatory read traffic; L3 serves ~half (FETCH ~152 MB from HBM).
//
// R1: 654 us atomic serialization -> partials + 2nd kernel (124 us).
// R2: latency-bound. R3: 2560 blocks, rolled, plain loads -> 119 us.
// R4: 64-VGPR cap -> scratch spill -> 228 us. NEVER cap below working set.
// R5: register double-buffer pipeline -> 118 us (all-reg path ~2.60 TB/s).
// R6: LDS-DMA + accidental vmcnt(0) drain -> 124 us. R7: drain fixed -> 124.5 us
//     (all-DMA path ~2.47 TB/s). R8: bursts/unroll1/direction-flip -> NULL
//     (flip defeated by workspace re-poison). Same-path concurrency exonerated.
// R9: PATH SPLIT: inputs (1/3 bytes) -> plain global_load->VGPR ping-pong;
//     mask+targets (2/3) stay LDS-DMA -> 110 us (~2.79 TB/s). CONFIRMED lever:
//     the VGPR-return and LDS-DMA-fill completion paths add. NT hint on inputs:
//     FETCH unchanged -> 'nt' does not shape L3; theory dead.
// R10 (this): BALANCE the two paths at 153.6 MB each. Reg path: inputs (2 KB/stage)
//     + mask half A (1 KB). DMA path: mask half B (1 KB) + targets (2 KB) + halo.
//     7 vmem/stage (3 reg + 4 DMA) keeps the counted vmcnt(7) exact. LDS shrinks to
//     3.2 KB/buffer -> 6 blocks/CU; grid 12x128 = 1536 = exact resident fill; NIT=9.
//     Predict: DMA-path critical time 205->154 MB => dur ~82-98 us if paths add;
//     flat => shared upstream limit, roofline case next.

#define B_DIM 128
#define T_DIM 200000

constexpr int BLOCK        = 256;
constexpr int WPB          = 4;                          // waves per block
constexpr int BLOCKS_X     = 12;                         // 12*128 = 1536 blocks = 6/CU exact
constexpr int WAVES_ROW    = BLOCKS_X * WPB;             // 48 waves sweep one row
constexpr int GROUPS_ROW   = T_DIM / 4;                  // 50000 float4/int4 groups
constexpr int LAST_G       = GROUPS_ROW - 1;             // 49999
constexpr int TILE_G       = 128;                        // groups per wave-stage (512 elems)
constexpr int NTILES       = (GROUPS_ROW + TILE_G - 1) / TILE_G;    // 391
constexpr int NIT          = (NTILES + WAVES_ROW - 1) / WAVES_ROW;  // 9 stages (odd)
constexpr int NUM_PARTIALS = BLOCKS_X * B_DIM;           // 1536

// Per-wave LDS buffer (x2 double-buffered):
//   m1 @ +0 (1024) | t0 @ +1024 (1024) | t1 @ +2048 (1024) | halo @ +3072 (32, pad)
constexpr int BUFB   = 3200;
constexpr int WBYTES = 2 * BUFB;                         // 6400/wave; 25600/block -> 6/CU

typedef float vf4 __attribute__((ext_vector_type(4)));

__device__ __forceinline__ void async16(void* lds, const void* g) {
    typedef const unsigned int __attribute__((address_space(1)))* GP;
    typedef unsigned int       __attribute__((address_space(3)))* LP;
    // HW: LDS dest = wave-uniform base + lane*16; global src is per-lane.
    __builtin_amdgcn_global_load_lds((GP)g, (LP)lds, 16, 0, 0);
}
__device__ __forceinline__ void async4(void* lds, const void* g) {
    typedef const unsigned int __attribute__((address_space(1)))* GP;
    typedef unsigned int       __attribute__((address_space(3)))* LP;
    __builtin_amdgcn_global_load_lds((GP)g, (LP)lds, 4, 0, 0);
}

__global__ __launch_bounds__(BLOCK) void bfl_main(
    const float* __restrict__ inputs,
    const int*   __restrict__ targets,
    const float* __restrict__ mask,
    float2*      __restrict__ partials)    // [NUM_PARTIALS] = (loss_sum, mask_sum)
{
    __shared__ int4  smem4[WPB * WBYTES / 16];
    __shared__ float sL[WPB];
    __shared__ float sM[WPB];

    const int b    = blockIdx.y;
    const int tid  = threadIdx.x;
    const int wid  = tid >> 6;
    const int lane = tid & 63;

    const long long row = (long long)b * T_DIM;
    const char* gx = (const char*)(inputs  + row);
    const char* gm = (const char*)(mask    + row);
    const char* gt = (const char*)(targets + row);

    char* wlds = (char*)smem4 + wid * WBYTES;
    const int tile0 = blockIdx.x * WPB + wid;            // [0, 48)

    float lsum = 0.0f, msum = 0.0f;

    // Register path (VGPR-return queue): inputs x2 + mask half A. 3 loads, 3 KB.
    auto xload = [&](int p, vf4& xa, vf4& xb, vf4& ma) {
        const int tb = (tile0 + p * WAVES_ROW) * TILE_G;
        const int g0 = min(max(tb + lane, 0), LAST_G);
        const int g1 = min(max(tb + 64 + lane, 0), LAST_G);
        xa = __builtin_nontemporal_load((const vf4*)(gx + g0 * 16));
        xb = __builtin_nontemporal_load((const vf4*)(gx + g1 * 16));
        ma = *(const vf4*)(gm + g0 * 16);
    };

    // DMA path (LDS-fill queue): mask half B + targets x2 + halo. 4 ops, ~3 KB.
    auto issue = [&](int p, int buf) {
        const int tb = (tile0 + p * WAVES_ROW) * TILE_G;
        const int g0 = min(max(tb + lane, 0), LAST_G);
        const int g1 = min(max(tb + 64 + lane, 0), LAST_G);
        char* dst = wlds + buf * BUFB;
        async16(dst,        gm + g1 * 16);               // m1
        async16(dst + 1024, gt + g0 * 16);               // t0
        async16(dst + 2048, gt + g1 * 16);               // t1
        // Halo: lanes 0-3 -> left int4 (group tb-1) at +3072, lanes 4-7 -> right
        // (group tb+128) at +3088, lanes 8-63 land in the pad.
        const int hl = min(max(tb - 1, 0), LAST_G);
        const int hr = min(max(tb + TILE_G, 0), LAST_G);
        const int ho = (lane < 4) ? (hl * 16 + lane * 4)
                     : (lane < 8) ? (hr * 16 + (lane - 4) * 4)
                     : 0;
        async4(dst + 3072, gt + ho);
    };

    // One 4-element group: transition mask, window-OR, focal loss.
    auto group = [&](const float4 x4, const float4 m4, int4 c, int4 pv, int4 nx,
                     int graw) {
        const bool valid = (graw < GROUPS_ROW);
        const float scale = valid ? 1.0f : 0.0f;
        const int g = valid ? graw : LAST_G;

        // Row-edge replicate: out-of-row transition bits compare-equal -> 0,
        // matching reference's zero-padded trans[0] and 'SAME' window clipping.
        if (g == 0)      { pv.x = c.x; pv.y = c.x; pv.z = c.x; pv.w = c.x; }
        if (g == LAST_G) { nx.x = c.w; nx.y = c.w; nx.z = c.w; }

        // mb bit j <-> transition at relative elem (j-3); elem i boundary = OR mb[i..i+6]
        unsigned mb = 0u;
        mb |= (pv.y != pv.x) ? 0x001u : 0u;
        mb |= (pv.z != pv.y) ? 0x002u : 0u;
        mb |= (pv.w != pv.z) ? 0x004u : 0u;
        mb |= (c.x  != pv.w) ? 0x008u : 0u;
        mb |= (c.y  != c.x ) ? 0x010u : 0u;
        mb |= (c.z  != c.y ) ? 0x020u : 0u;
        mb |= (c.w  != c.z ) ? 0x040u : 0u;
        mb |= (nx.x != c.w ) ? 0x080u : 0u;
        mb |= (nx.y != nx.x) ? 0x100u : 0u;
        mb |= (nx.z != nx.y) ? 0x200u : 0u;
        unsigned o = mb | (mb >> 1);
        o |= o >> 2;
        o |= o >> 3;

        auto elem = [&](float x, float mraw, int t, unsigned bit) {
            const float mm   = mraw * scale;
            const float posf = (float)t;                         // targets in {0,1}

            const float smoothed = fmaf(posf, 0.95f, 0.025f);    // pos*(1-ls)+ls/2
            const float alpha_w  = fmaf(posf, -0.5f, 0.75f);     // 0.25 pos + 0.75 neg
            const float w        = fmaf((float)bit, 4.0f, 1.0f); // 1 or 5

            // ea = exp(-|x|); sigmoid(|x|) = 1/(1+ea); |sigmoid(x)-0.5| = sigmoid(|x|)-0.5
            const float ea   = __expf(-fabsf(x));
            const float opea = 1.0f + ea;
            const float r    = __builtin_amdgcn_rcpf(opea);
            const float adaptive = 1.5f - r;

            const float bce = fmaf(-x, smoothed, fmaxf(x, 0.0f)) + __logf(opea);
            const float pt  = __expf(-bce);
            const float om  = 1.0f - pt;

            lsum = fmaf(alpha_w * om * om * bce * w * adaptive, mm, lsum);
            msum += mm;
        };

        elem(x4.x, m4.x, c.x, (o      ) & 1u);
        elem(x4.y, m4.y, c.y, (o >> 1 ) & 1u);
        elem(x4.z, m4.z, c.z, (o >> 2 ) & 1u);
        elem(x4.w, m4.w, c.w, (o >> 3 ) & 1u);
    };

    auto compute = [&](int p, int buf, const vf4 xa, const vf4 xb, const vf4 ma) {
        const char* base = wlds + buf * BUFB;
        const float4 m1 = *(const float4*)(base + lane * 16);
        const int4* tb4 = (const int4*)(base + 1024);
        const int4 c0 = tb4[lane];
        const int4 c1 = tb4[64 + lane];
        const int4 pv0 = (lane == 0)  ? *(const int4*)(base + 3072) : tb4[lane - 1];
        const int4 nx0 = tb4[lane + 1];                  // lane63 -> tb4[64] (group tb+64)
        const int4 pv1 = tb4[63 + lane];                 // lane0  -> tb4[63]
        const int4 nx1 = (lane == 63) ? *(const int4*)(base + 3088) : tb4[65 + lane];

        const float4 x0 = make_float4(xa.x, xa.y, xa.z, xa.w);
        const float4 x1 = make_float4(xb.x, xb.y, xb.z, xb.w);
        const float4 m0 = make_float4(ma.x, ma.y, ma.z, ma.w);

        const int tb = (tile0 + p * WAVES_ROW) * TILE_G;
        group(x0, m0, c0, pv0, nx0, tb + lane);
        group(x1, m1, c1, pv1, nx1, tb + 64 + lane);
    };

    vf4 xA0, xA1, mA, xB0, xB1, mB;

    // Prologue: stage 0 in flight (3 reg loads + 4 DMAs).
    xload(0, xA0, xA1, mA);
    issue(0, 0);

    // NIT = 9 (odd): pairs (0,1)..(6,7), then tail stage 8.
    #pragma unroll 1
    for (int it = 0; it < NIT - 1; it += 2) {
        // A-half: prefetch stage it+1, compute stage it (buf0, A-regs)
        xload(it + 1, xB0, xB1, mB);
        issue(it + 1, 1);
        // 14 vmem ops in flight; wait to <=7: stage it fully landed (both paths),
        // stage it+1's 7 ops REMAIN IN FLIGHT across this stall.
        asm volatile("s_waitcnt vmcnt(7)" ::: "memory");
        __builtin_amdgcn_sched_barrier(0);
        compute(it, 0, xA0, xA1, mA);

        // B-half: prefetch stage it+2, compute stage it+1 (buf1, B-regs)
        xload(it + 2, xA0, xA1, mA);
        issue(it + 2, 0);
        asm volatile("s_waitcnt vmcnt(7)" ::: "memory");
        __builtin_amdgcn_sched_barrier(0);
        compute(it + 1, 1, xB0, xB1, mB);
    }
    // Tail: stage 8 (loaded in the last B-half; lanes past NTILES clamped + zeroed).
    asm volatile("s_waitcnt vmcnt(0)" ::: "memory");
    __builtin_amdgcn_sched_barrier(0);
    compute(NIT - 1, 0, xA0, xA1, mA);

    // wave (64-lane) butterfly reduction
    #pragma unroll
    for (int off = 32; off > 0; off >>= 1) {
        lsum += __shfl_xor(lsum, off);
        msum += __shfl_xor(msum, off);
    }

    if (lane == 0) { sL[wid] = lsum; sM[wid] = msum; }
    __syncthreads();

    if (tid == 0) {
        float bl = 0.0f, bm = 0.0f;
        #pragma unroll
        for (int i = 0; i < WPB; ++i) { bl += sL[i]; bm += sM[i]; }
        partials[b * BLOCKS_X + blockIdx.x] = make_float2(bl, bm);
    }
}

__global__ __launch_bounds__(BLOCK) void bfl_reduce(
    const float2* __restrict__ partials,
    float*        __restrict__ out)
{
    float ls = 0.0f, ms = 0.0f;
    #pragma unroll
    for (int i = 0; i < NUM_PARTIALS / BLOCK; ++i) {
        const float2 p = partials[i * BLOCK + threadIdx.x];
        ls += p.x; ms += p.y;
    }

    #pragma unroll
    for (int off = 32; off > 0; off >>= 1) {
        ls += __shfl_xor(ls, off);
        ms += __shfl_xor(ms, off);
    }

    __shared__ float sL[BLOCK / 64];
    __shared__ float sM[BLOCK / 64];
    const int wave = threadIdx.x >> 6;
    const int lane = threadIdx.x & 63;
    if (lane == 0) { sL[wave] = ls; sM[wave] = ms; }
    __syncthreads();

    if (threadIdx.x == 0) {
        float bl = 0.0f, bm = 0.0f;
        #pragma unroll
        for (int i = 0; i < BLOCK / 64; ++i) { bl += sL[i]; bm += sM[i]; }
        out[0] = (bm > 0.0f) ? (bl / bm) : 0.0f;
    }
}

extern "C" void kernel_launch(void* const* d_in, const int* in_sizes, int n_in,
                              void* d_out, int out_size, void* d_ws, size_t ws_size,
                              hipStream_t stream) {
    const float* inputs   = (const float*)d_in[0];
    const int*   targets  = (const int*)d_in[1];
    const float* mask     = (const float*)d_in[2];
    float*       out      = (float*)d_out;
    float2*      partials = (float2*)d_ws;

    dim3 grid(BLOCKS_X, B_DIM);
    bfl_main<<<grid, BLOCK, 0, stream>>>(inputs, targets, mask, partials);
    bfl_reduce<<<1, BLOCK, 0, stream>>>(partials, out);
}

// Round 6
// 286.040 us; speedup vs baseline: 1.0203x; 1.0203x over previous
//
#include <hip/hip_runtime.h>
#include <math.h>

// BoundaryFocalLoss: B=128, T=200000, f32 inputs, i32 targets, f32 mask -> scalar f32.
// ~307 MB mandatory read traffic; L3 serves ~half (FETCH ~152 MB from HBM).
//
// R1: 654 us atomic serialization -> partials + 2nd kernel (124 us).
// R2: latency-bound. R3: 2560 blocks, rolled, plain loads -> 119 us.
// R4: 64-VGPR cap -> scratch spill -> 228 us. NEVER cap below working set.
// R5: register double-buffer pipeline -> 118 us (all-reg ~2.60 TB/s).
// R6: LDS-DMA + accidental vmcnt(0) drain -> 124 us. R7: drain fixed -> 124.5 us
//     (all-DMA ~2.47 TB/s). R8: bursts/unroll1/direction-flip -> NULL.
// R9: PATH SPLIT inputs->reg (NT), mask+targets->DMA -> 110 us (~2.79 TB/s). BEST.
// R10: balanced 50/50 split + 6/CU -> 115.6 us. REGRESSED: additive-queue model
//     dead; optimum is R9's 67% DMA share. Reference data (m13 copy 3.15 TB/s/dir,
//     RMSNorm ~2.4/dir, us 2.79 read-only) all cluster ~2.4-3.2 TB/s per direction
//     -> per-direction ingress ceiling downstream of L3 (L3 hits don't beat it).
// R11 (this): restore R9 geometry exactly (8 blocks_x, NIT=13, 67/33 split) and
//     delete the async4 halo DMA (a full request slot + 256 B fetch for 32 useful
//     bytes every stage). Halo now = two wave-uniform int4 reg loads (16 B lines,
//     fully useful) issued with the reg batch, consumed a stage later (oldest in
//     flight at use -> no drain). DMA ops/stage 5->4; counted wait vmcnt(8).
//     Predict 103-109 us; if ~110 flat, request-count lever dead -> roofline case.

#define B_DIM 128
#define T_DIM 200000

constexpr int BLOCK        = 256;
constexpr int WPB          = 4;                          // waves per block
constexpr int BLOCKS_X     = 8;                          // 8*128 = 1024 blocks = 4/CU exact
constexpr int WAVES_ROW    = BLOCKS_X * WPB;             // 32 waves sweep one row
constexpr int GROUPS_ROW   = T_DIM / 4;                  // 50000 float4/int4 groups
constexpr int LAST_G       = GROUPS_ROW - 1;             // 49999
constexpr int TILE_G       = 128;                        // groups per wave-stage
constexpr int NTILES       = (GROUPS_ROW + TILE_G - 1) / TILE_G;    // 391
constexpr int NIT          = (NTILES + WAVES_ROW - 1) / WAVES_ROW;  // 13 stages (odd)
constexpr int NUM_PARTIALS = BLOCKS_X * B_DIM;           // 1024

// Per-wave LDS buffer (x2 double-buffered): m @ +0 (2048) | t @ +2048 (2048)
constexpr int BUFB   = 4096;
constexpr int WBYTES = 2 * BUFB;                         // 8192/wave; 32768/block -> 4/CU

typedef float vf4 __attribute__((ext_vector_type(4)));

__device__ __forceinline__ void async16(void* lds, const void* g) {
    typedef const unsigned int __attribute__((address_space(1)))* GP;
    typedef unsigned int       __attribute__((address_space(3)))* LP;
    // HW: LDS dest = wave-uniform base + lane*16; global src is per-lane.
    __builtin_amdgcn_global_load_lds((GP)g, (LP)lds, 16, 0, 0);
}

__global__ __launch_bounds__(BLOCK) void bfl_main(
    const float* __restrict__ inputs,
    const int*   __restrict__ targets,
    const float* __restrict__ mask,
    float2*      __restrict__ partials)    // [NUM_PARTIALS] = (loss_sum, mask_sum)
{
    __shared__ int4  smem4[WPB * WBYTES / 16];
    __shared__ float sL[WPB];
    __shared__ float sM[WPB];

    const int b    = blockIdx.y;
    const int tid  = threadIdx.x;
    const int wid  = tid >> 6;
    const int lane = tid & 63;

    const long long row = (long long)b * T_DIM;
    const char* gx  = (const char*)(inputs  + row);
    const char* gm  = (const char*)(mask    + row);
    const char* gt  = (const char*)(targets + row);
    const int4* pt4 = (const int4*)gt;

    char* wlds = (char*)smem4 + wid * WBYTES;
    const int tile0 = blockIdx.x * WPB + wid;            // [0, 32)

    float lsum = 0.0f, msum = 0.0f;

    // Register path: inputs x2 (NT) + two wave-uniform halo int4s. 4 reg loads.
    auto xload = [&](int p, vf4& xa, vf4& xb, int4& hl, int4& hr) {
        const int tb = (tile0 + p * WAVES_ROW) * TILE_G;
        const int g0 = min(max(tb + lane, 0), LAST_G);
        const int g1 = min(max(tb + 64 + lane, 0), LAST_G);
        xa = __builtin_nontemporal_load((const vf4*)(gx + g0 * 16));
        xb = __builtin_nontemporal_load((const vf4*)(gx + g1 * 16));
        hl = pt4[min(max(tb - 1, 0), LAST_G)];           // group tb-1 (uniform)
        hr = pt4[min(max(tb + TILE_G, 0), LAST_G)];      // group tb+128 (uniform)
    };

    // DMA path (LDS-fill queue): mask x2 + targets x2. 4 fire-and-forget ops.
    auto issue = [&](int p, int buf) {
        const int tb = (tile0 + p * WAVES_ROW) * TILE_G;
        const int g0 = min(max(tb + lane, 0), LAST_G);
        const int g1 = min(max(tb + 64 + lane, 0), LAST_G);
        char* dst = wlds + buf * BUFB;
        async16(dst,        gm + g0 * 16);               // m0
        async16(dst + 1024, gm + g1 * 16);               // m1
        async16(dst + 2048, gt + g0 * 16);               // t0
        async16(dst + 3072, gt + g1 * 16);               // t1
    };

    // One 4-element group: transition mask, window-OR, focal loss.
    auto group = [&](const float4 x4, const float4 m4, int4 c, int4 pv, int4 nx,
                     int graw) {
        const bool valid = (graw < GROUPS_ROW);
        const float scale = valid ? 1.0f : 0.0f;
        const int g = valid ? graw : LAST_G;

        // Row-edge replicate: out-of-row transition bits compare-equal -> 0,
        // matching reference's zero-padded trans[0] and 'SAME' window clipping.
        if (g == 0)      { pv.x = c.x; pv.y = c.x; pv.z = c.x; pv.w = c.x; }
        if (g == LAST_G) { nx.x = c.w; nx.y = c.w; nx.z = c.w; }

        // mb bit j <-> transition at relative elem (j-3); elem i boundary = OR mb[i..i+6]
        unsigned mb = 0u;
        mb |= (pv.y != pv.x) ? 0x001u : 0u;
        mb |= (pv.z != pv.y) ? 0x002u : 0u;
        mb |= (pv.w != pv.z) ? 0x004u : 0u;
        mb |= (c.x  != pv.w) ? 0x008u : 0u;
        mb |= (c.y  != c.x ) ? 0x010u : 0u;
        mb |= (c.z  != c.y ) ? 0x020u : 0u;
        mb |= (c.w  != c.z ) ? 0x040u : 0u;
        mb |= (nx.x != c.w ) ? 0x080u : 0u;
        mb |= (nx.y != nx.x) ? 0x100u : 0u;
        mb |= (nx.z != nx.y) ? 0x200u : 0u;
        unsigned o = mb | (mb >> 1);
        o |= o >> 2;
        o |= o >> 3;

        auto elem = [&](float x, float mraw, int t, unsigned bit) {
            const float mm   = mraw * scale;
            const float posf = (float)t;                         // targets in {0,1}

            const float smoothed = fmaf(posf, 0.95f, 0.025f);    // pos*(1-ls)+ls/2
            const float alpha_w  = fmaf(posf, -0.5f, 0.75f);     // 0.25 pos + 0.75 neg
            const float w        = fmaf((float)bit, 4.0f, 1.0f); // 1 or 5

            // ea = exp(-|x|); sigmoid(|x|) = 1/(1+ea); |sigmoid(x)-0.5| = sigmoid(|x|)-0.5
            const float ea   = __expf(-fabsf(x));
            const float opea = 1.0f + ea;
            const float r    = __builtin_amdgcn_rcpf(opea);
            const float adaptive = 1.5f - r;

            const float bce = fmaf(-x, smoothed, fmaxf(x, 0.0f)) + __logf(opea);
            const float pt  = __expf(-bce);
            const float om  = 1.0f - pt;

            lsum = fmaf(alpha_w * om * om * bce * w * adaptive, mm, lsum);
            msum += mm;
        };

        elem(x4.x, m4.x, c.x, (o      ) & 1u);
        elem(x4.y, m4.y, c.y, (o >> 1 ) & 1u);
        elem(x4.z, m4.z, c.z, (o >> 2 ) & 1u);
        elem(x4.w, m4.w, c.w, (o >> 3 ) & 1u);
    };

    auto compute = [&](int p, int buf, const vf4 xa, const vf4 xb,
                       const int4 hl, const int4 hr) {
        const char* base = wlds + buf * BUFB;
        const float4 m0 = *(const float4*)(base +        lane * 16);
        const float4 m1 = *(const float4*)(base + 1024 + lane * 16);
        const int4* tb4 = (const int4*)(base + 2048);
        const int4 c0 = tb4[lane];
        const int4 c1 = tb4[64 + lane];
        const int4 pv0 = (lane == 0)  ? hl : tb4[lane - 1];
        const int4 nx0 = tb4[lane + 1];                  // lane63 -> tb4[64] (group tb+64)
        const int4 pv1 = tb4[63 + lane];                 // lane0  -> tb4[63]
        const int4 nx1 = (lane == 63) ? hr : tb4[65 + lane];

        const float4 x0 = make_float4(xa.x, xa.y, xa.z, xa.w);
        const float4 x1 = make_float4(xb.x, xb.y, xb.z, xb.w);

        const int tb = (tile0 + p * WAVES_ROW) * TILE_G;
        group(x0, m0, c0, pv0, nx0, tb + lane);
        group(x1, m1, c1, pv1, nx1, tb + 64 + lane);
    };

    vf4 xA0, xA1, xB0, xB1;
    int4 hlA, hrA, hlB, hrB;

    // Prologue: stage 0 in flight (4 reg loads + 4 DMAs).
    xload(0, xA0, xA1, hlA, hrA);
    issue(0, 0);

    // NIT = 13 (odd): pairs (0,1)..(10,11), then tail stage 12.
    #pragma unroll 1
    for (int it = 0; it < NIT - 1; it += 2) {
        // A-half: prefetch stage it+1, compute stage it (buf0, A-regs)
        xload(it + 1, xB0, xB1, hlB, hrB);
        issue(it + 1, 1);
        // 16 vmem ops in flight; wait to <=8: stage it fully landed (both paths),
        // stage it+1's 8 ops REMAIN IN FLIGHT across this stall.
        asm volatile("s_waitcnt vmcnt(8)" ::: "memory");
        __builtin_amdgcn_sched_barrier(0);
        compute(it, 0, xA0, xA1, hlA, hrA);

        // B-half: prefetch stage it+2, compute stage it+1 (buf1, B-regs)
        xload(it + 2, xA0, xA1, hlA, hrA);
        issue(it + 2, 0);
        asm volatile("s_waitcnt vmcnt(8)" ::: "memory");
        __builtin_amdgcn_sched_barrier(0);
        compute(it + 1, 1, xB0, xB1, hlB, hrB);
    }
    // Tail: stage 12 (loaded in the last B-half; lanes past NTILES clamped + zeroed).
    asm volatile("s_waitcnt vmcnt(0)" ::: "memory");
    __builtin_amdgcn_sched_barrier(0);
    compute(NIT - 1, 0, xA0, xA1, hlA, hrA);

    // wave (64-lane) butterfly reduction
    #pragma unroll
    for (int off = 32; off > 0; off >>= 1) {
        lsum += __shfl_xor(lsum, off);
        msum += __shfl_xor(msum, off);
    }

    if (lane == 0) { sL[wid] = lsum; sM[wid] = msum; }
    __syncthreads();

    if (tid == 0) {
        float bl = 0.0f, bm = 0.0f;
        #pragma unroll
        for (int i = 0; i < WPB; ++i) { bl += sL[i]; bm += sM[i]; }
        partials[b * BLOCKS_X + blockIdx.x] = make_float2(bl, bm);
    }
}

__global__ __launch_bounds__(BLOCK) void bfl_reduce(
    const float2* __restrict__ partials,
    float*        __restrict__ out)
{
    float ls = 0.0f, ms = 0.0f;
    #pragma unroll
    for (int i = 0; i < NUM_PARTIALS / BLOCK; ++i) {
        const float2 p = partials[i * BLOCK + threadIdx.x];
        ls += p.x; ms += p.y;
    }

    #pragma unroll
    for (int off = 32; off > 0; off >>= 1) {
        ls += __shfl_xor(ls, off);
        ms += __shfl_xor(ms, off);
    }

    __shared__ float sL[BLOCK / 64];
    __shared__ float sM[BLOCK / 64];
    const int wave = threadIdx.x >> 6;
    const int lane = threadIdx.x & 63;
    if (lane == 0) { sL[wave] = ls; sM[wave] = ms; }
    __syncthreads();

    if (threadIdx.x == 0) {
        float bl = 0.0f, bm = 0.0f;
        #pragma unroll
        for (int i = 0; i < BLOCK / 64; ++i) { bl += sL[i]; bm += sM[i]; }
        out[0] = (bm > 0.0f) ? (bl / bm) : 0.0f;
    }
}

extern "C" void kernel_launch(void* const* d_in, const int* in_sizes, int n_in,
                              void* d_out, int out_size, void* d_ws, size_t ws_size,
                              hipStream_t stream) {
    const float* inputs   = (const float*)d_in[0];
    const int*   targets  = (const int*)d_in[1];
    const float* mask     = (const float*)d_in[2];
    float*       out      = (float*)d_out;
    float2*      partials = (float2*)d_ws;

    dim3 grid(BLOCKS_X, B_DIM);
    bfl_main<<<grid, BLOCK, 0, stream>>>(inputs, targets, mask, partials);
    bfl_reduce<<<1, BLOCK, 0, stream>>>(partials, out);
}